// Round 7
// baseline (1001.873 us; speedup 1.0000x reference)
//
#include <hip/hip_runtime.h>
#include <hip/hip_bf16.h>

typedef short short8_v __attribute__((ext_vector_type(8)));
typedef float f32x4 __attribute__((ext_vector_type(4)));

#define QC 576  // padded qkva column stride: q[0,256) val[256,512) act[512,556) pad[556,576)

// fragment-swizzled layout: element (r,k) of an [R][K] operand ->
// tile (r/16, k/32), lane = (r%16) + 16*((k%32)/8), elem = k%8
__device__ __forceinline__ size_t swz_e(int r, int k, int KC) {
  return ((size_t)((r >> 4) * KC + (k >> 5)) * 64 + (r & 15) + (((k >> 3) & 3) << 4)) * 8 + (k & 7);
}

__device__ __forceinline__ float wave_sum(float v) {
#pragma unroll
  for (int off = 32; off > 0; off >>= 1) v += __shfl_xor(v, off);
  return v;
}

__device__ __forceinline__ float sigf(float x) { return 1.f / (1.f + __expf(-x)); }
// fast tanh via __expf: exact at saturation
__device__ __forceinline__ float tfast(float x) {
  float e = __expf(2.f * x);
  return 1.f - 2.f / (e + 1.f);
}

// relaxed agent-scope atomics: L1-bypassing, coherent across XCDs
template <typename T>
__device__ __forceinline__ T ald(const T* p) {
  return __hip_atomic_load(p, __ATOMIC_RELAXED, __HIP_MEMORY_SCOPE_AGENT);
}
template <typename T>
__device__ __forceinline__ void ast(T* p, T v) {
  __hip_atomic_store(p, v, __ATOMIC_RELAXED, __HIP_MEMORY_SCOPE_AGENT);
}

// ---------------- prologue kernels (once per call) ----------------

__global__ void prep_weights(const float* __restrict__ W_ih, const float* __restrict__ W_hh,
                             __hip_bfloat16* __restrict__ Wcat) {
  int idx = blockIdx.x * blockDim.x + threadIdx.x;  // 1024*512
  if (idx >= 1024 * 512) return;
  int jj = idx >> 9, k = idx & 511;
  int chunk = jj >> 6, gate = (jj >> 4) & 3, r = jj & 15;
  int j = gate * 256 + chunk * 16 + r;
  float v = (k < 256) ? W_ih[j * 256 + k] : W_hh[j * 256 + (k - 256)];
  Wcat[swz_e(jj, k, 16)] = __float2bfloat16(v);
}

__global__ void prep_wq(const float* __restrict__ Wq_w, const float* __restrict__ Wq_b,
                        __hip_bfloat16* __restrict__ Wq, float* __restrict__ biasq) {
  int idx = blockIdx.x * blockDim.x + threadIdx.x;  // 576*256
  if (idx >= 576 * 256) return;
  int n = idx >> 8, k = idx & 255;
  int orig = (n < 256) ? n : (n < 556 ? n + 256 : -1);
  float v = (orig >= 0) ? Wq_w[orig * 256 + k] : 0.f;
  Wq[swz_e(n, k, 8)] = __float2bfloat16(v);
  if (k == 0) biasq[n] = (orig >= 0) ? Wq_b[orig] : 0.f;
}

__global__ void prep_tgt(const float* __restrict__ tgt, __hip_bfloat16* __restrict__ tswz) {
  for (size_t idx = (size_t)blockIdx.x * blockDim.x + threadIdx.x; idx < (size_t)128 * 131072;
       idx += (size_t)gridDim.x * blockDim.x) {
    int t = (int)(idx >> 17);
    int rem = (int)(idx & 131071);
    int b = rem >> 8, k = rem & 255;
    tswz[(size_t)t * 131072 + swz_e(b, k, 8)] = __float2bfloat16(tgt[idx]);
  }
}

__global__ void reset_bars(unsigned* __restrict__ bars) {
  int i = blockIdx.x * blockDim.x + threadIdx.x;
  if (i < 2048) bars[i] = 0u;
}

// ---------------- persistent kernel (regular launch; co-residency by resource math:
// 2 x 79872B LDS = 159744 <= 163840 per CU, VGPR<=256, 8 waves/CU -> all 512 resident) ----------
// grid 512 x 256 (2 blocks/CU). Group m (0..31) = 16 blocks {m + 32*cgrp}, cgrp 0..15.
// Block (m,cgrp): 4 tape pairs (b = 16m+cgrp, tp = wave 0..3),
//   gates slice rows [16m,16m+16) x h-cols [16cgrp,16cgrp+16) (all 4 gates; wave = gate),
//   qkva tiles [qst, qst+qcnt), qcnt = cgrp<4 ? 3 : 2.
// Phase p: gates(p)+LSTM->h(p) || qkva(p-1) || arrive || tape(p-2) || poll.
// LDS (floats): tape 4*[64 rows][16 chunks]f32x4 XOR-swizzled @0 (16384 f) ;
//   WS 4*[64]f2 @16384 (512 f) ; gbuf [4][16][16] @16896 (1024 f, qn aliases) ;
//   hstage [8][64][8]bf16 @17920 (2048 f) ; total 19968 f = 79872 B -> 2 blocks/CU
#define DYN_LDS 79872

__global__ __launch_bounds__(256, 2) void persist(
    const short8_v* __restrict__ tswz, const short8_v* __restrict__ Wcat,
    const short8_v* __restrict__ Wq, const float* __restrict__ biasq,
    const float* __restrict__ b_ih, const float* __restrict__ b_hh,
    unsigned short* __restrict__ hG,  // 2 x 131072 bf16 (frag-swizzled), dbuf
    float* __restrict__ qkva,         // 2 x 512*QC f32, dbuf
    float* __restrict__ out, const float* __restrict__ src, unsigned* __restrict__ bars) {
  extern __shared__ float lds[];
  const int tid = threadIdx.x;
  const int w = tid >> 6, lane = tid & 63;
  const int m = blockIdx.x & 31, cgrp = blockIdx.x >> 5;
  unsigned* grpbar = bars + m * 64;

  f32x4* Tc = (f32x4*)lds + (size_t)w * 1024;  // tape [64][16] chunks, phys ch = c4^(row&15)
  float* WS = lds + 16384 + w * 128;           // {wp, rs} f2 per row, current step
  float* gbuf = lds + 16896;                   // [4 gates][16 rows][16 cols]
  float* QN = lds + 16896 + w * 64;            // qn scratch (aliases gbuf; used post-epilogue)
  unsigned long long* hstage_u64 = (unsigned long long*)(lds + 17920);
  const short8_v* hstage_s8 = (const short8_v*)(lds + 17920);

  const int g = lane >> 4, c4 = lane & 15;

  // ---- tape pair identity + init ----
  const int b = 16 * m + cgrp;
  const int tp = w;
#pragma unroll
  for (int i = 0; i < 16; ++i) {
    int row = i * 4 + g;
    f32x4 v = *(const f32x4*)(src + (size_t)row * 131072 + b * 256 + tp * 64 + c4 * 4);
    Tc[row * 16 + (c4 ^ (row & 15))] = v;
  }
  float rp = (lane == 0) ? 1.f : 0.f, wp = rp;
  float wpPrev = 0.f;                    // wpos of previous tape step (for pending rank-1)
  f32x4 dvp4 = {0.f, 0.f, 0.f, 0.f};     // pending rank-1 dv (this lane's 4 cols)
  bool bar_ok = true;                    // escape valve: disabled after first timeout

  // ---- epilogue roles: thread -> one h value (row = tid>>4, colLocal = tid&15) ----
  const int erow = tid >> 4, ecol = tid & 15;
  const int jh = 16 * cgrp + ecol;
  const float bI = b_ih[jh] + b_hh[jh];
  const float bF = b_ih[256 + jh] + b_hh[256 + jh];
  const float bG_ = b_ih[512 + jh] + b_hh[512 + jh];
  const float bO = b_ih[768 + jh] + b_hh[768 + jh];
  float c_reg = 0.f;
  const unsigned hIdx32 =
      (unsigned)(((m * 8 + (jh >> 5)) * 64 + erow + 16 * ((jh >> 3) & 3)) * 4 + ((jh >> 1) & 3));

  // ---- qkva tile assignment ----
  const int qcnt = (cgrp < 4) ? 3 : 2;
  const int qst = (cgrp < 4) ? 3 * cgrp : 12 + 2 * (cgrp - 4);
  const int qtile = qst + w;  // valid if w < qcnt

  // ---- hoisted loop-invariant operands (registers) ----
  short8_v bFr[16];
#pragma unroll
  for (int kc = 0; kc < 16; ++kc) bFr[kc] = Wcat[((4 * cgrp + w) * 16 + kc) * 64 + lane];
  short8_v bQ[8];
  float bqv = 0.f;
  int n0 = 0;
  if (w < qcnt) {
    n0 = qtile * 16 + (lane & 15);
    bqv = biasq[n0];
#pragma unroll
    for (int kc = 0; kc < 8; ++kc) bQ[kc] = Wq[(qtile * 8 + kc) * 64 + lane];
  }

#pragma unroll 1
  for (int p = 0; p <= 129; ++p) {
    const int hrd = (p + 1) & 1, hwr = p & 1;
    const int s = p - 2;  // tape step

    // ---- early issue: tape's qkva-row loads (L3) ----
    float a_[11];
    f32x4 q4, val4;
    if (s >= 0) {
      const float* qrow = qkva + (size_t)(s & 1) * (512 * QC) + (size_t)b * QC;
#pragma unroll
      for (int j = 0; j < 11; ++j) a_[j] = ald(qrow + 512 + tp * 11 + j);
      unsigned long long u0 = ald((const unsigned long long*)(qrow + tp * 64 + c4 * 4));
      unsigned long long u1 = ald((const unsigned long long*)(qrow + tp * 64 + c4 * 4 + 2));
      unsigned long long v0 = ald((const unsigned long long*)(qrow + 256 + tp * 64 + c4 * 4));
      unsigned long long v1 = ald((const unsigned long long*)(qrow + 256 + tp * 64 + c4 * 4 + 2));
      float2 qa = __builtin_bit_cast(float2, u0), qb = __builtin_bit_cast(float2, u1);
      float2 va = __builtin_bit_cast(float2, v0), vb = __builtin_bit_cast(float2, v1);
      q4 = (f32x4){qa.x, qa.y, qb.x, qb.y};
      val4 = (f32x4){va.x, va.y, vb.x, vb.y};
    }
    // ---- gates A operands ----
    short8_v aF[8];
    if (p < 128) {
      const short8_v* xg = tswz + (size_t)p * 16384;
#pragma unroll
      for (int kc = 0; kc < 8; ++kc) aF[kc] = xg[(m * 8 + kc) * 64 + lane];
    }
    // ---- stage h(p-1) into LDS (contiguous 8KB m-tile copy; tile = u64 [m*1024, +1024)) ----
    if (p >= 1 && p <= 128) {
      const unsigned long long* hsrc =
          (const unsigned long long*)(hG + (size_t)hrd * 131072) + (size_t)m * 1024;
#pragma unroll
      for (int j = 0; j < 4; ++j) {
        unsigned long long v = ald(hsrc + tid + 256 * j);
        hstage_u64[tid + 256 * j] = v;
      }
    }
    __syncthreads();  // hstage ready; prev-phase gbuf/hstage uses complete
    // ---- gates MFMA -> gbuf (wave w = gate w, one 16x16 tile) ----
    if (p < 128) {
      f32x4 acc = {0.f, 0.f, 0.f, 0.f};
#pragma unroll
      for (int kc = 0; kc < 8; ++kc)
        acc = __builtin_amdgcn_mfma_f32_16x16x32_bf16(aF[kc], bFr[kc], acc, 0, 0, 0);
      if (p > 0) {
#pragma unroll
        for (int kc = 8; kc < 16; ++kc) {
          short8_v a = hstage_s8[(kc - 8) * 64 + lane];
          acc = __builtin_amdgcn_mfma_f32_16x16x32_bf16(a, bFr[kc], acc, 0, 0, 0);
        }
      }
#pragma unroll
      for (int r = 0; r < 4; ++r)
        gbuf[(w * 16 + ((lane >> 4) * 4 + r)) * 16 + (lane & 15)] = acc[r];
    }
    __syncthreads();  // gbuf ready
    // ---- LSTM epilogue -> h(p) ----
    if (p < 128) {
      float gi = gbuf[(0 * 16 + erow) * 16 + ecol] + bI;
      float gf = gbuf[(1 * 16 + erow) * 16 + ecol] + bF;
      float gg = gbuf[(2 * 16 + erow) * 16 + ecol] + bG_;
      float go = gbuf[(3 * 16 + erow) * 16 + ecol] + bO;
      float cc = sigf(gf) * c_reg + sigf(gi) * tfast(gg);
      c_reg = cc;
      float hh = sigf(go) * tfast(cc);
      __hip_bfloat16 hb16 = __float2bfloat16(hh);
      unsigned own = (unsigned)(*(unsigned short*)&hb16);
      unsigned other = (unsigned)__shfl_xor((int)own, 1) & 0xFFFFu;
      if ((ecol & 1) == 0) {
        unsigned pack = (other << 16) | own;
        ast((unsigned*)(hG + (size_t)hwr * 131072) + hIdx32, pack);
      }
    }
    // ---- qkva MFMA for step p-1 (A from hstage) ----
    if (p >= 1 && p <= 128 && w < qcnt) {
      f32x4 qa = {0.f, 0.f, 0.f, 0.f};
#pragma unroll
      for (int kc = 0; kc < 8; ++kc)
        qa = __builtin_amdgcn_mfma_f32_16x16x32_bf16(hstage_s8[kc * 64 + lane], bQ[kc], qa, 0, 0, 0);
      float* qw = qkva + (size_t)((p - 1) & 1) * (512 * QC);
#pragma unroll
      for (int r = 0; r < 4; ++r)
        ast(&qw[(size_t)(16 * m + (lane >> 4) * 4 + r) * QC + n0], qa[r] + bqv);
    }
    // ---- drain stores, arrive at group barrier, THEN do tape (hides barrier) ----
    asm volatile("s_waitcnt vmcnt(0)" ::: "memory");
    __syncthreads();
    if (tid == 0 && p < 129)
      __hip_atomic_fetch_add(grpbar, 1u, __ATOMIC_RELAXED, __HIP_MEMORY_SCOPE_AGENT);
    // ---- tape compute for step s ----
    if (s >= 0) {
      float m1 = fmaxf(fmaxf(a_[0], a_[1]), fmaxf(a_[2], a_[3]));
      float e0 = __expf(a_[0] - m1), e1 = __expf(a_[1] - m1), e2 = __expf(a_[2] - m1),
            e3 = __expf(a_[3] - m1);
      float inv = 1.f / (e0 + e1 + e2 + e3);
      float rd0 = e0 * inv, rd1 = e1 * inv, rd2 = e2 * inv, rd3 = e3 * inv;
      float m2 = fmaxf(fmaxf(a_[4], a_[5]), fmaxf(a_[6], a_[7]));
      float f0 = __expf(a_[4] - m2), f1 = __expf(a_[5] - m2), f2 = __expf(a_[6] - m2),
            f3 = __expf(a_[7] - m2);
      float inv2 = 1.f / (f0 + f1 + f2 + f3);
      float wd0 = f0 * inv2, wd1 = f1 * inv2, wd2 = f2 * inv2, wd3 = f3 * inv2;
      float rwe0 = sigf(a_[8]), rwe1 = sigf(a_[9]), rwe2 = sigf(a_[10]);
      // qn: normalize q over 64 cols (lane holds 4 cols; reduce across c4)
      float ss = q4[0] * q4[0] + q4[1] * q4[1] + q4[2] * q4[2] + q4[3] * q4[3];
#pragma unroll
      for (int off = 1; off < 16; off <<= 1) ss += __shfl_xor(ss, off);
      float qninv = 1.f / fmaxf(sqrtf(ss), 1e-12f);
      f32x4 qn4 = q4 * qninv;
      // stage per-row {wp, rs} (lane=row) and qn (g==0 lanes)
      *(float2*)&WS[lane * 2] = make_float2(wp, rp * rwe0);
      if (g == 0) *(f32x4*)&QN[c4 * 4] = qn4;
      // row pass: apply pending rank-1 (wpPrev broadcast via shfl), reduce oldval & rval
      f32x4 oa = {0.f, 0.f, 0.f, 0.f}, ra = oa;
#pragma unroll
      for (int i = 0; i < 16; ++i) {
        int row = i * 4 + g;
        float wO = __shfl(wpPrev, row);
        float2 wrN = *(const float2*)&WS[row * 2];
        int ti = row * 16 + (c4 ^ (row & 15));
        f32x4 v = Tc[ti];
        v += wO * dvp4;
        Tc[ti] = v;
        oa += wrN.x * v;
        ra += wrN.y * v;
      }
#pragma unroll
      for (int off = 16; off <= 32; off <<= 1) {
        f32x4 t;
        t[0] = __shfl_xor(oa[0], off); t[1] = __shfl_xor(oa[1], off);
        t[2] = __shfl_xor(oa[2], off); t[3] = __shfl_xor(oa[3], off);
        oa += t;
        t[0] = __shfl_xor(ra[0], off); t[1] = __shfl_xor(ra[1], off);
        t[2] = __shfl_xor(ra[2], off); t[3] = __shfl_xor(ra[3], off);
        ra += t;
      }
      dvp4 = val4 * rwe1 - oa * rwe2;  // next step's pending rank-1 (lane-local)
      if (g == 0)
        *(f32x4*)(out + (size_t)s * 131072 + b * 256 + tp * 64 + c4 * 4) = ra;
      // col pass: jq[row=lane] = sum_c T[row][c]*qn[c]
      float jq = 0.f;
#pragma unroll
      for (int j = 0; j < 16; ++j) {
        f32x4 v = Tc[lane * 16 + (j ^ (lane & 15))];
        f32x4 qv = *(const f32x4*)&QN[j * 4];
        jq += v[0] * qv[0] + v[1] * qv[1] + v[2] * qv[2] + v[3] * qv[3];
      }
      float jsum = wave_sum(jq * jq);
      float jp = jq / fmaxf(sqrtf(jsum), 1e-12f);
      // roll(x,1)[i]=x[i-1] (next_*), roll(x,-1)[i]=x[i+1] (prev_*)
      float next_w = __shfl(wp, (lane + 63) & 63);
      float prev_w = __shfl(wp, (lane + 1) & 63);
      float next_r = __shfl(rp, (lane + 63) & 63);
      float prev_r = __shfl(rp, (lane + 1) & 63);
      wpPrev = wp;  // this step's wpos, pending for step s+1
      wp = prev_w * wd0 + wp * wd1 + next_w * wd2 + jp * wd3;
      rp = prev_r * rd0 + rp * rd1 + next_r * rd2 + jp * rd3;
    }
    // ---- wait for group (tape overlapped most of the skew) ----
    if (p < 129) {
      __syncthreads();
      if (tid == 0) {
        unsigned target = 16u * (unsigned)(p + 1);
        if (bar_ok) {
          long long t0 = (long long)__builtin_amdgcn_s_memrealtime();
          while (ald(grpbar) < target) {
            __builtin_amdgcn_s_sleep(8);
            if ((long long)__builtin_amdgcn_s_memrealtime() - t0 > 100000000LL) {
              bar_ok = false;  // ~1s escape valve: never hang, fail with diagnostic absmax
              break;
            }
          }
        }
        asm volatile("" ::: "memory");
      }
      __syncthreads();
    }
  }
}

// ---------------- host ----------------

extern "C" void kernel_launch(void* const* d_in, const int* in_sizes, int n_in, void* d_out,
                              int out_size, void* d_ws, size_t ws_size, hipStream_t stream) {
  const float* tgt = (const float*)d_in[0];
  const float* src = (const float*)d_in[1];
  const float* W_ih = (const float*)d_in[2];
  const float* W_hh = (const float*)d_in[3];
  const float* b_ih = (const float*)d_in[4];
  const float* b_hh = (const float*)d_in[5];
  const float* Wq_w = (const float*)d_in[6];
  const float* Wq_b = (const float*)d_in[7];
  float* out = (float*)d_out;

  char* ws = (char*)d_ws;
  size_t off = 0;
  auto alloc = [&](size_t bytes) -> void* {
    void* p = ws + off;
    off = (off + bytes + 255) & ~(size_t)255;
    return p;
  };
  unsigned* bars = (unsigned*)alloc(2048 * 4);
  float* qkva = (float*)alloc((size_t)2 * 512 * QC * 4);
  unsigned short* hG = (unsigned short*)alloc((size_t)2 * 131072 * 2);
  __hip_bfloat16* Wcat = (__hip_bfloat16*)alloc((size_t)1024 * 512 * 2);
  __hip_bfloat16* Wq = (__hip_bfloat16*)alloc((size_t)576 * 256 * 2);
  float* biasq = (float*)alloc((size_t)576 * 4);
  __hip_bfloat16* tswz = (__hip_bfloat16*)alloc((size_t)128 * 131072 * 2);

  reset_bars<<<8, 256, 0, stream>>>(bars);
  prep_weights<<<2048, 256, 0, stream>>>(W_ih, W_hh, Wcat);
  prep_wq<<<576, 256, 0, stream>>>(Wq_w, Wq_b, Wq, biasq);
  prep_tgt<<<8192, 256, 0, stream>>>(tgt, tswz);

  hipFuncSetAttribute((const void*)persist, hipFuncAttributeMaxDynamicSharedMemorySize, DYN_LDS);

  // Regular (non-cooperative) launch: no grid-wide sync is used — only 16-block group
  // barriers — and resource math guarantees all 512 blocks co-resident (2/CU).
  persist<<<dim3(512), dim3(256), DYN_LDS, stream>>>(
      (const short8_v*)tswz, (const short8_v*)Wcat, (const short8_v*)Wq, biasq, b_ih, b_hh, hG,
      qkva, out, src, bars);
}